// Round 3
// baseline (948.293 us; speedup 1.0000x reference)
//
#include <hip/hip_runtime.h>

#define T_STEPS 200
#define BATCH   256
#define HCH     2
#define H1      200
#define SPL1    392
#define OCH     4
#define NOUTC   10
#define SPL2    50
#define M_TOTAL (T_STEPS*BATCH)   // 51200

// ---------------------------------------------------------------------
// Workspace layout (bytes):
//   CUR  : [51200][2][200] f32      = 81,920,000
//   S    : [51200][4][64]  u8       = 13,107,200  (64B oc slices -> uint4-aligned)
//   CURO : [51200][40]     f32      =  8,192,000  (col = j*4 + oc)
// total ~103.2 MB
// ---------------------------------------------------------------------

// =====================================================================
// Kernel 1: CUR[m,c,n] = sum_i X[m, c*392+i] * Wh[c,n,i] + bh[c,n]
// fp32 VALU GEMM, M=51200, N=200 (full width per block), K=392.
// BM=80, BN=200, BK=8; 250/256 active threads, 8x8 thread tile
// (cols = colg*2 + jp*50 + e : float2 groups at stride 50 -> <=2-way LDS
// bank aliasing). Double-buffered LDS, ONE barrier per K-tile, next
// tile's global loads issued before compute (latency hidden under FMAs).
// K-order per output is strictly sequential -> bitwise-identical result.
// =====================================================================
#define BK 8

__global__ __launch_bounds__(256, 3)
void k1_gemm(const float* __restrict__ X, const float* __restrict__ Wh,
             const float* __restrict__ bh, float* __restrict__ CUR)
{
    __shared__ float As[2][BK][80];    // 2 x 2560 B
    __shared__ float Ws[2][BK][200];   // 2 x 6400 B
    const int tid = threadIdx.x;
    const int m0 = blockIdx.x * 80;
    const int c  = blockIdx.y;
    const bool active = tid < 250;
    const int rowg = tid / 25;         // 0..9, 8 rows each
    const int colg = tid % 25;         // 0..24, cols colg*2 + jp*50 + e

    const float* Xc = X  + (size_t)m0 * (HCH*SPL1) + c*SPL1;
    const float* Wc = Wh + (size_t)c * H1 * SPL1;

    float ra[3], rw[7];   // staging regs (A: 640 = 2*256+128; W: 1600 = 6*256+64)

    auto stage_load = [&](int k0) {
#pragma unroll
        for (int r = 0; r < 3; ++r) {
            int idx = tid + 256*r;
            if (idx < 640) ra[r] = Xc[(size_t)(idx >> 3)*(HCH*SPL1) + k0 + (idx & 7)];
        }
#pragma unroll
        for (int r = 0; r < 7; ++r) {
            int idx = tid + 256*r;
            if (idx < 1600) rw[r] = Wc[(size_t)(idx >> 3)*SPL1 + k0 + (idx & 7)];
        }
    };
    auto stage_store = [&](int p) {
#pragma unroll
        for (int r = 0; r < 3; ++r) {
            int idx = tid + 256*r;
            if (idx < 640) As[p][idx & 7][idx >> 3] = ra[r];
        }
#pragma unroll
        for (int r = 0; r < 7; ++r) {
            int idx = tid + 256*r;
            if (idx < 1600) Ws[p][idx & 7][idx >> 3] = rw[r];
        }
    };

    float acc[8][8];
#pragma unroll
    for (int i = 0; i < 8; ++i)
#pragma unroll
        for (int j = 0; j < 8; ++j) acc[i][j] = 0.f;

    stage_load(0);
    stage_store(0);
    __syncthreads();

    int p = 0;
    for (int t = 0; t < SPL1/BK; ++t) {          // 49 K-tiles
        if (t < SPL1/BK - 1) stage_load((t+1)*BK);   // issue early: hides latency
        if (active) {
#pragma unroll
            for (int k = 0; k < BK; ++k) {
                float4 a0 = *(const float4*)&As[p][k][rowg*8];
                float4 a1 = *(const float4*)&As[p][k][rowg*8 + 4];
                float2 w0 = *(const float2*)&Ws[p][k][colg*2];
                float2 w1 = *(const float2*)&Ws[p][k][colg*2 + 50];
                float2 w2 = *(const float2*)&Ws[p][k][colg*2 + 100];
                float2 w3 = *(const float2*)&Ws[p][k][colg*2 + 150];
                float av[8] = {a0.x, a0.y, a0.z, a0.w, a1.x, a1.y, a1.z, a1.w};
                float wv[8] = {w0.x, w0.y, w1.x, w1.y, w2.x, w2.y, w3.x, w3.y};
#pragma unroll
                for (int i = 0; i < 8; ++i)
#pragma unroll
                    for (int j = 0; j < 8; ++j)
                        acc[i][j] = __builtin_fmaf(av[i], wv[j], acc[i][j]);
            }
        }
        if (t < SPL1/BK - 1) stage_store(p ^ 1);  // waits vmcnt internally
        __syncthreads();                          // single barrier per tile
        p ^= 1;
    }

    if (active) {
#pragma unroll
        for (int i = 0; i < 8; ++i) {
            size_t m = m0 + rowg*8 + i;
            size_t base = (m*HCH + c)*H1 + colg*2;
#pragma unroll
            for (int jp = 0; jp < 4; ++jp) {
                int gn = colg*2 + jp*50;
                float2 v;
                v.x = __fadd_rn(acc[i][jp*2+0], bh[c*H1 + gn + 0]);
                v.y = __fadd_rn(acc[i][jp*2+1], bh[c*H1 + gn + 1]);
                *(float2*)&CUR[base + jp*50] = v;
            }
        }
    }
}

// =====================================================================
// Kernel 2: hidden LIF recurrence, sequential over T, thread = (b,h).
// Depth-8 register prefetch ring (static indices via full unroll).
// Exact-order fp32 (verified absmax==0.0 in round 2).
// =====================================================================
__global__ __launch_bounds__(256)
void k2_lif(const float* __restrict__ CUR, unsigned char* __restrict__ S)
{
    const int tid = blockIdx.x * 256 + threadIdx.x;  // 0..51199
    const int b = tid / H1;
    const int h = tid - b*H1;
    const size_t cbase = (size_t)b*(HCH*H1) + h;
    const int    soff  = b*(OCH*64) + (h/SPL2)*64 + (h%SPL2);
    const size_t tstr  = (size_t)BATCH*HCH*H1;            // 102400
    const size_t sstr  = (size_t)BATCH*OCH*64;            // 65536

    float c0[8], c1[8];
#pragma unroll
    for (int pp = 0; pp < 8; ++pp) {
        c0[pp] = CUR[(size_t)pp*tstr + cbase];
        c1[pp] = CUR[(size_t)pp*tstr + cbase + H1];
    }

    float vh0 = 0.f, ih0 = 0.f, vh1 = 0.f, ih1 = 0.f;

    for (int tb = 0; tb < T_STEPS; tb += 8) {
#pragma unroll
        for (int u = 0; u < 8; ++u) {
            const int t = tb + u;
            float cc0 = c0[u], cc1 = c1[u];
            if (t + 8 < T_STEPS) {
                c0[u] = CUR[(size_t)(t+8)*tstr + cbase];
                c1[u] = CUR[(size_t)(t+8)*tstr + cbase + H1];
            }
            float vd0 = __fadd_rn(vh0, __fmul_rn(0.1f, __fsub_rn(ih0, vh0)));
            float vd1 = __fadd_rn(vh1, __fmul_rn(0.1f, __fsub_rn(ih1, vh1)));
            int z0 = vd0 > 1.0f;
            int z1 = vd1 > 1.0f;
            vh0 = z0 ? 0.f : vd0;
            vh1 = z1 ? 0.f : vd1;
            ih0 = __fadd_rn(__fmul_rn(ih0, 0.8f), cc0);
            ih1 = __fadd_rn(__fmul_rn(ih1, 0.8f), cc1);
            S[(size_t)t*sstr + soff] = (unsigned char)(z0 + z1);
        }
    }
}

// =====================================================================
// Kernel 3: cur_o[r, j*4+oc] = sum_i s[r,oc,i]*Wo[oc,j,i] + bo[oc,j]
// 4 rows x 5 j per thread; Wo in LDS (b128 reads on 8 distinct bank
// quads); S read from global as uint4 (u8x16, 64B-aligned slices).
// =====================================================================
__global__ __launch_bounds__(256)
void k3_outgemm(const unsigned char* __restrict__ S, const float* __restrict__ Wo,
                const float* __restrict__ bo, float* __restrict__ CURO)
{
    __shared__ float sW[OCH*NOUTC][52];   // row stride 208B
    const int tid = threadIdx.x;
    for (int idx = tid; idx < OCH*NOUTC*SPL2; idx += 256)
        sW[idx/SPL2][idx%SPL2] = Wo[idx];
    __syncthreads();

    const int rowg = tid >> 3;          // 0..31
    const int colg = tid & 7;
    const int oc = colg & 3;
    const int jg = colg >> 2;           // j = jg*5 + jj
    const int cl0 = oc*NOUTC + jg*5;
    const int r0 = blockIdx.x*128 + rowg*4;
    const unsigned char* sp = S + (size_t)r0*(OCH*64) + oc*64;

    float acc[4][5];
#pragma unroll
    for (int rr = 0; rr < 4; ++rr)
#pragma unroll
        for (int jj = 0; jj < 5; ++jj) acc[rr][jj] = 0.f;

#define B2F(w, bb) ((float)(((w) >> (8*(bb))) & 255u))

#pragma unroll
    for (int rr = 0; rr < 4; ++rr) {
        const unsigned char* rp = sp + (size_t)rr*(OCH*64);
        uint4 u0 = *(const uint4*)(rp);
        uint4 u1 = *(const uint4*)(rp + 16);
        uint4 u2 = *(const uint4*)(rp + 32);
        unsigned short ut = *(const unsigned short*)(rp + 48);
        unsigned int uw[13] = {u0.x,u0.y,u0.z,u0.w, u1.x,u1.y,u1.z,u1.w,
                               u2.x,u2.y,u2.z,u2.w, (unsigned int)ut};
#pragma unroll
        for (int q = 0; q < 12; ++q) {
            float s0 = B2F(uw[q],0), s1 = B2F(uw[q],1);
            float s2 = B2F(uw[q],2), s3 = B2F(uw[q],3);
#pragma unroll
            for (int jj = 0; jj < 5; ++jj) {
                float4 w = *(const float4*)&sW[cl0+jj][q*4];
                float a = acc[rr][jj];
                a = __builtin_fmaf(s0, w.x, a);
                a = __builtin_fmaf(s1, w.y, a);
                a = __builtin_fmaf(s2, w.z, a);
                a = __builtin_fmaf(s3, w.w, a);
                acc[rr][jj] = a;
            }
        }
        // tail i = 48,49
        float s48 = B2F(uw[12],0), s49 = B2F(uw[12],1);
#pragma unroll
        for (int jj = 0; jj < 5; ++jj) {
            float2 wt = *(const float2*)&sW[cl0+jj][48];
            float a = acc[rr][jj];
            a = __builtin_fmaf(s48, wt.x, a);
            a = __builtin_fmaf(s49, wt.y, a);
            acc[rr][jj] = a;
        }
    }
#pragma unroll
    for (int rr = 0; rr < 4; ++rr)
#pragma unroll
        for (int jj = 0; jj < 5; ++jj) {
            int j = jg*5 + jj;
            CURO[(size_t)(r0+rr)*(OCH*NOUTC) + j*4 + oc] =
                __fadd_rn(acc[rr][jj], bo[oc*NOUTC + j]);
        }
}

// =====================================================================
// Kernel 4: output LI recurrence + oc-sum. Thread = (b,j) owns 4 oc
// channels as one float4 column; depth-8 float4 prefetch ring.
// =====================================================================
__global__ __launch_bounds__(64)
void k4_li(const float* __restrict__ CURO, float* __restrict__ OUT)
{
    const int tid = blockIdx.x*64 + threadIdx.x;   // 0..2559 = b*10+j
    const float4* C4 = (const float4*)CURO;

    float4 ring[8];
#pragma unroll
    for (int pp = 0; pp < 8; ++pp) ring[pp] = C4[(size_t)pp*2560 + tid];

    float vo0=0.f, vo1=0.f, vo2=0.f, vo3=0.f;
    float io0=0.f, io1=0.f, io2=0.f, io3=0.f;

    for (int tb = 0; tb < T_STEPS; tb += 8) {
#pragma unroll
        for (int u = 0; u < 8; ++u) {
            const int t = tb + u;
            float4 cv = ring[u];
            if (t + 8 < T_STEPS) ring[u] = C4[(size_t)(t+8)*2560 + tid];
            vo0 = __fadd_rn(vo0, __fmul_rn(0.1f, __fsub_rn(io0, vo0)));
            vo1 = __fadd_rn(vo1, __fmul_rn(0.1f, __fsub_rn(io1, vo1)));
            vo2 = __fadd_rn(vo2, __fmul_rn(0.1f, __fsub_rn(io2, vo2)));
            vo3 = __fadd_rn(vo3, __fmul_rn(0.1f, __fsub_rn(io3, vo3)));
            io0 = __fadd_rn(__fmul_rn(io0, 0.8f), cv.x);
            io1 = __fadd_rn(__fmul_rn(io1, 0.8f), cv.y);
            io2 = __fadd_rn(__fmul_rn(io2, 0.8f), cv.z);
            io3 = __fadd_rn(__fmul_rn(io3, 0.8f), cv.w);
            float s = __fadd_rn(__fadd_rn(__fadd_rn(vo0, vo1), vo2), vo3);
            OUT[(size_t)t*2560 + tid] = s;
        }
    }
}

// =====================================================================
extern "C" void kernel_launch(void* const* d_in, const int* in_sizes, int n_in,
                              void* d_out, int out_size, void* d_ws, size_t ws_size,
                              hipStream_t stream)
{
    const float* X  = (const float*)d_in[0];   // [200,256,28,28]
    const float* Wh = (const float*)d_in[1];   // [2,200,392]
    const float* bh = (const float*)d_in[2];   // [2,200]
    const float* Wo = (const float*)d_in[3];   // [4,10,50]
    const float* bo = (const float*)d_in[4];   // [4,10]
    float* OUT = (float*)d_out;                // [200,256,10]

    char* ws = (char*)d_ws;
    float*         CUR  = (float*)ws;                               // 81,920,000
    unsigned char* S    = (unsigned char*)(ws + 81920000);          // 13,107,200
    float*         CURO = (float*)(ws + 81920000 + 13107200);       //  8,192,000

    k1_gemm   <<<dim3(M_TOTAL/80, HCH), 256, 0, stream>>>(X, Wh, bh, CUR);
    k2_lif    <<<M_TOTAL/256,           256, 0, stream>>>(CUR, S);
    k3_outgemm<<<M_TOTAL/128,           256, 0, stream>>>(S, Wo, bo, CURO);
    k4_li     <<<(BATCH*NOUTC)/64,      64,  0, stream>>>(CURO, OUT);
}

// Round 6
// 498.908 us; speedup vs baseline: 1.9007x; 1.9007x over previous
//
#include <hip/hip_runtime.h>

#define T_STEPS 200
#define BATCH   256
#define HCH     2
#define H1      200
#define SPL1    392
#define OCH     4
#define NOUTC   10
#define SPL2    50
#define M_TOTAL (T_STEPS*BATCH)   // 51200

// ---------------------------------------------------------------------
// [R6 = R4 resubmission; R4 and R5 never ran (GPU acquisition timeouts).]
// Workspace layout (bytes):
//   CUR  : [51200][2][200] f32      = 81,920,000
//   S    : [51200][4][64]  u8       = 13,107,200  (64B oc slices, uint4-aligned)
//   CURO : [51200][40]     f32      =  8,192,000  (col = j*4 + oc)
// ---------------------------------------------------------------------

// =====================================================================
// Kernel 1: CUR[m,c,n] = sum_i X[m, c*392+i] * Wh[c,n,i] + bh[c,n]
// fp32 VALU GEMM. BM=80, BN=100 (grid.y=2), BK=8. 250/256 threads,
// 8 rows x 4 cols per thread (acc=32 VGPR -> no spill; round-3 lesson).
// Double-buffered LDS, T14 async-stage: global loads issued BEFORE
// compute (named scalars, no arrays), ds_write after, 1 barrier/tile.
// Zero masked FMAs (80|51200, 100|200, 8|392). K strictly sequential
// per output -> bitwise-exact vs reference (absmax 0.0 in R2).
// =====================================================================
#define BK 8

__global__ __launch_bounds__(256)
void k1_gemm(const float* __restrict__ X, const float* __restrict__ Wh,
             const float* __restrict__ bh, float* __restrict__ CUR)
{
    __shared__ float As[2][BK][80];    // 2 x 2560 B
    __shared__ float Ws[2][BK][100];   // 2 x 3200 B
    const int tid = threadIdx.x;
    const int m0 = blockIdx.x * 80;
    const int n0 = blockIdx.y * 100;
    const int c  = blockIdx.z;
    const bool active = tid < 250;
    const int rowg = tid / 25;         // 0..9 -> rows rowg*8 .. +7
    const int colg = tid % 25;         // 0..24 -> cols colg*4 .. +3

    const float* Xc = X  + (size_t)m0 * (HCH*SPL1) + c*SPL1;
    const float* Wc = Wh + (size_t)c * H1 * SPL1 + (size_t)n0 * SPL1;

    // staging decomposition: idx = tid + 256*r -> k = tid&7 (const),
    // row = (tid>>3) + 32*r.  A: 640 floats (r=0,1 full; r=2 tid<128).
    // W: 800 floats (r=0..2 full; r=3 tid<32).
    const int kA    = tid & 7;
    const int rbase = tid >> 3;        // 0..31
    const bool a2v = (tid < 128);
    const bool w3v = (tid < 32);
    const size_t xstr = (size_t)(HCH*SPL1);

    float ra0, ra1, ra2, rw0, rw1, rw2, rw3;

    float acc[8][4];
#pragma unroll
    for (int i = 0; i < 8; ++i)
#pragma unroll
        for (int j = 0; j < 4; ++j) acc[i][j] = 0.f;

    // prologue: stage tile 0
    {
        const int k0 = 0;
        ra0 = Xc[(size_t)(rbase +  0)*xstr + k0 + kA];
        ra1 = Xc[(size_t)(rbase + 32)*xstr + k0 + kA];
        ra2 = a2v ? Xc[(size_t)(rbase + 64)*xstr + k0 + kA] : 0.f;
        rw0 = Wc[(size_t)(rbase +  0)*SPL1 + k0 + kA];
        rw1 = Wc[(size_t)(rbase + 32)*SPL1 + k0 + kA];
        rw2 = Wc[(size_t)(rbase + 64)*SPL1 + k0 + kA];
        rw3 = w3v ? Wc[(size_t)(rbase + 96)*SPL1 + k0 + kA] : 0.f;
        As[0][kA][rbase +  0] = ra0;
        As[0][kA][rbase + 32] = ra1;
        if (a2v) As[0][kA][rbase + 64] = ra2;
        Ws[0][kA][rbase +  0] = rw0;
        Ws[0][kA][rbase + 32] = rw1;
        Ws[0][kA][rbase + 64] = rw2;
        if (w3v) Ws[0][kA][rbase + 96] = rw3;
    }
    __syncthreads();

    int p = 0;
    for (int t = 0; t < SPL1/BK; ++t) {          // 49 K-tiles
        const bool more = (t < SPL1/BK - 1);
        if (more) {                               // issue early (hide under FMAs)
            const int k0 = (t+1)*BK;
            ra0 = Xc[(size_t)(rbase +  0)*xstr + k0 + kA];
            ra1 = Xc[(size_t)(rbase + 32)*xstr + k0 + kA];
            ra2 = a2v ? Xc[(size_t)(rbase + 64)*xstr + k0 + kA] : 0.f;
            rw0 = Wc[(size_t)(rbase +  0)*SPL1 + k0 + kA];
            rw1 = Wc[(size_t)(rbase + 32)*SPL1 + k0 + kA];
            rw2 = Wc[(size_t)(rbase + 64)*SPL1 + k0 + kA];
            rw3 = w3v ? Wc[(size_t)(rbase + 96)*SPL1 + k0 + kA] : 0.f;
        }
        if (active) {
#pragma unroll
            for (int k = 0; k < BK; ++k) {
                float4 a0 = *(const float4*)&As[p][k][rowg*8];
                float4 a1 = *(const float4*)&As[p][k][rowg*8 + 4];
                float4 w  = *(const float4*)&Ws[p][k][colg*4];
                float av[8] = {a0.x, a0.y, a0.z, a0.w, a1.x, a1.y, a1.z, a1.w};
                float wv[4] = {w.x, w.y, w.z, w.w};
#pragma unroll
                for (int i = 0; i < 8; ++i)
#pragma unroll
                    for (int j = 0; j < 4; ++j)
                        acc[i][j] = __builtin_fmaf(av[i], wv[j], acc[i][j]);
            }
        }
        if (more) {                               // ds_write after compute
            const int q = p ^ 1;
            As[q][kA][rbase +  0] = ra0;
            As[q][kA][rbase + 32] = ra1;
            if (a2v) As[q][kA][rbase + 64] = ra2;
            Ws[q][kA][rbase +  0] = rw0;
            Ws[q][kA][rbase + 32] = rw1;
            Ws[q][kA][rbase + 64] = rw2;
            if (w3v) Ws[q][kA][rbase + 96] = rw3;
        }
        __syncthreads();                          // single barrier per tile
        p ^= 1;
    }

    if (active) {
        const int gn = n0 + colg*4;
        float4 bias = *(const float4*)&bh[c*H1 + gn];
#pragma unroll
        for (int i = 0; i < 8; ++i) {
            size_t m = m0 + rowg*8 + i;
            float4 v;
            v.x = __fadd_rn(acc[i][0], bias.x);
            v.y = __fadd_rn(acc[i][1], bias.y);
            v.z = __fadd_rn(acc[i][2], bias.z);
            v.w = __fadd_rn(acc[i][3], bias.w);
            *(float4*)&CUR[(m*HCH + c)*H1 + gn] = v;
        }
    }
}

// =====================================================================
// Kernel 2: hidden LIF recurrence, sequential over T, thread = (b,h).
// Depth-10 register prefetch ring (200 % 10 == 0; static indices).
// Exact-order fp32 (verified absmax==0.0).
// =====================================================================
__global__ __launch_bounds__(256)
void k2_lif(const float* __restrict__ CUR, unsigned char* __restrict__ S)
{
    const int tid = blockIdx.x * 256 + threadIdx.x;  // 0..51199
    const int b = tid / H1;
    const int h = tid - b*H1;
    const size_t cbase = (size_t)b*(HCH*H1) + h;
    const int    soff  = b*(OCH*64) + (h/SPL2)*64 + (h%SPL2);
    const size_t tstr  = (size_t)BATCH*HCH*H1;            // 102400
    const size_t sstr  = (size_t)BATCH*OCH*64;            // 65536

    float c0[10], c1[10];
#pragma unroll
    for (int pp = 0; pp < 10; ++pp) {
        c0[pp] = CUR[(size_t)pp*tstr + cbase];
        c1[pp] = CUR[(size_t)pp*tstr + cbase + H1];
    }

    float vh0 = 0.f, ih0 = 0.f, vh1 = 0.f, ih1 = 0.f;

    for (int tb = 0; tb < T_STEPS; tb += 10) {
#pragma unroll
        for (int u = 0; u < 10; ++u) {
            const int t = tb + u;
            float cc0 = c0[u], cc1 = c1[u];
            if (t + 10 < T_STEPS) {
                c0[u] = CUR[(size_t)(t+10)*tstr + cbase];
                c1[u] = CUR[(size_t)(t+10)*tstr + cbase + H1];
            }
            float vd0 = __fadd_rn(vh0, __fmul_rn(0.1f, __fsub_rn(ih0, vh0)));
            float vd1 = __fadd_rn(vh1, __fmul_rn(0.1f, __fsub_rn(ih1, vh1)));
            int z0 = vd0 > 1.0f;
            int z1 = vd1 > 1.0f;
            vh0 = z0 ? 0.f : vd0;
            vh1 = z1 ? 0.f : vd1;
            ih0 = __fadd_rn(__fmul_rn(ih0, 0.8f), cc0);
            ih1 = __fadd_rn(__fmul_rn(ih1, 0.8f), cc1);
            S[(size_t)t*sstr + soff] = (unsigned char)(z0 + z1);
        }
    }
}

// =====================================================================
// Kernel 3: cur_o[r, j*4+oc] = sum_i s[r,oc,i]*Wo[oc,j,i] + bo[oc,j]
// 4 rows x 5 j per thread; Wo in LDS; S read from global as uint4.
// =====================================================================
__global__ __launch_bounds__(256)
void k3_outgemm(const unsigned char* __restrict__ S, const float* __restrict__ Wo,
                const float* __restrict__ bo, float* __restrict__ CURO)
{
    __shared__ float sW[OCH*NOUTC][52];   // row stride 208B
    const int tid = threadIdx.x;
    for (int idx = tid; idx < OCH*NOUTC*SPL2; idx += 256)
        sW[idx/SPL2][idx%SPL2] = Wo[idx];
    __syncthreads();

    const int rowg = tid >> 3;          // 0..31
    const int colg = tid & 7;
    const int oc = colg & 3;
    const int jg = colg >> 2;           // j = jg*5 + jj
    const int cl0 = oc*NOUTC + jg*5;
    const int r0 = blockIdx.x*128 + rowg*4;
    const unsigned char* sp = S + (size_t)r0*(OCH*64) + oc*64;

    float acc[4][5];
#pragma unroll
    for (int rr = 0; rr < 4; ++rr)
#pragma unroll
        for (int jj = 0; jj < 5; ++jj) acc[rr][jj] = 0.f;

#define B2F(w, bb) ((float)(((w) >> (8*(bb))) & 255u))

#pragma unroll
    for (int rr = 0; rr < 4; ++rr) {
        const unsigned char* rp = sp + (size_t)rr*(OCH*64);
        uint4 u0 = *(const uint4*)(rp);
        uint4 u1 = *(const uint4*)(rp + 16);
        uint4 u2 = *(const uint4*)(rp + 32);
        unsigned short ut = *(const unsigned short*)(rp + 48);
        unsigned int uw[13] = {u0.x,u0.y,u0.z,u0.w, u1.x,u1.y,u1.z,u1.w,
                               u2.x,u2.y,u2.z,u2.w, (unsigned int)ut};
#pragma unroll
        for (int q = 0; q < 12; ++q) {
            float s0 = B2F(uw[q],0), s1 = B2F(uw[q],1);
            float s2 = B2F(uw[q],2), s3 = B2F(uw[q],3);
#pragma unroll
            for (int jj = 0; jj < 5; ++jj) {
                float4 w = *(const float4*)&sW[cl0+jj][q*4];
                float a = acc[rr][jj];
                a = __builtin_fmaf(s0, w.x, a);
                a = __builtin_fmaf(s1, w.y, a);
                a = __builtin_fmaf(s2, w.z, a);
                a = __builtin_fmaf(s3, w.w, a);
                acc[rr][jj] = a;
            }
        }
        float s48 = B2F(uw[12],0), s49 = B2F(uw[12],1);
#pragma unroll
        for (int jj = 0; jj < 5; ++jj) {
            float2 wt = *(const float2*)&sW[cl0+jj][48];
            float a = acc[rr][jj];
            a = __builtin_fmaf(s48, wt.x, a);
            a = __builtin_fmaf(s49, wt.y, a);
            acc[rr][jj] = a;
        }
    }
#pragma unroll
    for (int rr = 0; rr < 4; ++rr)
#pragma unroll
        for (int jj = 0; jj < 5; ++jj) {
            int j = jg*5 + jj;
            CURO[(size_t)(r0+rr)*(OCH*NOUTC) + j*4 + oc] =
                __fadd_rn(acc[rr][jj], bo[oc*NOUTC + j]);
        }
}

// =====================================================================
// Kernel 4: output LI recurrence + oc-sum. Thread = (b,j) owns 4 oc
// channels as one float4 column; depth-8 float4 prefetch ring.
// =====================================================================
__global__ __launch_bounds__(64)
void k4_li(const float* __restrict__ CURO, float* __restrict__ OUT)
{
    const int tid = blockIdx.x*64 + threadIdx.x;   // 0..2559 = b*10+j
    const float4* C4 = (const float4*)CURO;

    float4 ring[8];
#pragma unroll
    for (int pp = 0; pp < 8; ++pp) ring[pp] = C4[(size_t)pp*2560 + tid];

    float vo0=0.f, vo1=0.f, vo2=0.f, vo3=0.f;
    float io0=0.f, io1=0.f, io2=0.f, io3=0.f;

    for (int tb = 0; tb < T_STEPS; tb += 8) {
#pragma unroll
        for (int u = 0; u < 8; ++u) {
            const int t = tb + u;
            float4 cv = ring[u];
            if (t + 8 < T_STEPS) ring[u] = C4[(size_t)(t+8)*2560 + tid];
            vo0 = __fadd_rn(vo0, __fmul_rn(0.1f, __fsub_rn(io0, vo0)));
            vo1 = __fadd_rn(vo1, __fmul_rn(0.1f, __fsub_rn(io1, vo1)));
            vo2 = __fadd_rn(vo2, __fmul_rn(0.1f, __fsub_rn(io2, vo2)));
            vo3 = __fadd_rn(vo3, __fmul_rn(0.1f, __fsub_rn(io3, vo3)));
            io0 = __fadd_rn(__fmul_rn(io0, 0.8f), cv.x);
            io1 = __fadd_rn(__fmul_rn(io1, 0.8f), cv.y);
            io2 = __fadd_rn(__fmul_rn(io2, 0.8f), cv.z);
            io3 = __fadd_rn(__fmul_rn(io3, 0.8f), cv.w);
            float s = __fadd_rn(__fadd_rn(__fadd_rn(vo0, vo1), vo2), vo3);
            OUT[(size_t)t*2560 + tid] = s;
        }
    }
}

// =====================================================================
extern "C" void kernel_launch(void* const* d_in, const int* in_sizes, int n_in,
                              void* d_out, int out_size, void* d_ws, size_t ws_size,
                              hipStream_t stream)
{
    const float* X  = (const float*)d_in[0];   // [200,256,28,28]
    const float* Wh = (const float*)d_in[1];   // [2,200,392]
    const float* bh = (const float*)d_in[2];   // [2,200]
    const float* Wo = (const float*)d_in[3];   // [4,10,50]
    const float* bo = (const float*)d_in[4];   // [4,10]
    float* OUT = (float*)d_out;                // [200,256,10]

    char* ws = (char*)d_ws;
    float*         CUR  = (float*)ws;                               // 81,920,000
    unsigned char* S    = (unsigned char*)(ws + 81920000);          // 13,107,200
    float*         CURO = (float*)(ws + 81920000 + 13107200);       //  8,192,000

    k1_gemm   <<<dim3(M_TOTAL/80, 2, HCH), 256, 0, stream>>>(X, Wh, bh, CUR);
    k2_lif    <<<M_TOTAL/256,              256, 0, stream>>>(CUR, S);
    k3_outgemm<<<M_TOTAL/128,              256, 0, stream>>>(S, Wo, bo, CURO);
    k4_li     <<<(BATCH*NOUTC)/64,         64,  0, stream>>>(CURO, OUT);
}